// Round 12
// baseline (899.617 us; speedup 1.0000x reference)
//
#include <hip/hip_runtime.h>
#include <cmath>

#define NS 64
#define NN 128
#define NT 1000
#define CH 8                                // steps per obuf half-buffer
#define PD 4                                // register prefetch depth
#define NNP 129                             // padded flush-row stride (bank-free)
#define WROWS 130                           // 128 rows of w + 2 zero rows
#define WL_DW (WROWS * NN)                  // 16640 (shared by both samples)
#define OB_HALF (3 * CH * NNP)              // 3096 dwords per half-buffer
#define OBUF_PS (2 * OB_HALF)               // 6192 per sample
#define LDS_BYTES ((WL_DW + 2 * OBUF_PS + 16) * 4)   // 116224

// == npy_logaddexpf(x, 0), branch-free but bit-identical:
//   x>0: fmax=x, |x|=x  -> x + log1p(exp(-x)) ; x<0: 0 + log1p(exp(x)) ; x==0 -> LOGE2
__device__ __forceinline__ float softplus_np(float x) {
    float r = fmaxf(x, 0.0f) + log1pf(expf(-fabsf(x)));
    return (x == 0.0f) ? 0.693147180559945309f : r;
}

// Barrier WITHOUT the compiler's vmcnt(0) drain: LDS-visibility only.
__device__ __forceinline__ void sync_lds() {
    asm volatile("s_waitcnt lgkmcnt(0)" ::: "memory");
    __builtin_amdgcn_s_barrier();
    asm volatile("" ::: "memory");
}

__global__ __launch_bounds__(192) void snn_scan_kernel(
    const float* __restrict__ w,
    const float* __restrict__ ic,
    const float* __restrict__ v0,
    const float* __restrict__ i0,
    const float* __restrict__ s0,
    const float* __restrict__ mu,
    const float* __restrict__ sigma,
    const float* __restrict__ noise,      // [T, S, N, 2]
    const float* __restrict__ exp_draws,  // [T, S, N]
    float* __restrict__ out)              // [S, N, T, 3]
{
    #pragma clang fp contract(off)
    extern __shared__ float smem[];
    float* wl   = smem;                   // [130][128]: w rows + 2 zero rows
    float* obuf = smem + WL_DW;           // [2 samp][2 half][3*CH][NNP]
    unsigned long long* mslot =           // [2 parity][2 samp][2 wave] u64
        (unsigned long long*)(smem + WL_DW + 2 * OBUF_PS);

    const int tid  = threadIdx.x;
    const int wid  = tid >> 6;            // waves 0,1 = compute; wave 2 = flush
    const int l    = tid & 63;
    const int n    = (wid << 6) | l;      // own neuron (compute waves)
    const int sampA = blockIdx.x * 2;     // this WG runs samples A and A+1

    if (tid < 128) {                      // stage w + zero rows (one-time)
        const float4* src = (const float4*)w;
        float4* dst = (float4*)wl;
        #pragma unroll
        for (int it = 0; it < 32; ++it)
            dst[it * 128 + tid] = src[it * 128 + tid];
        ((float2*)(wl + NN * NN))[tid] = make_float2(0.0f, 0.0f);
    }

    const float SQDT  = sqrtf(0.01f);     // 0x3DCCCCCD == np.sqrt(float32(0.01))
    const float DTf   = 0.01f;
    const float LOGE2 = 0.693147180559945309f;

    float* outbA = out + (size_t)sampA * NN * NT * 3;   // B = A + NN*NT*3

    float mu1 = 0.f, negmu2 = 0.f, g00 = 0.f, g01 = 0.f, g10 = 0.f, g11 = 0.f;
    float icn = 0.f;
    float vA = 0.f, iA = 0.f, sA = 0.f, spA = 0.f;      // sample A chain
    float vB = 0.f, iB = 0.f, sB = 0.f, spB = 0.f;      // sample B chain
    float2 nA0 = {}, nA1 = {}, nA2 = {}, nA3 = {};
    float2 nB0 = {}, nB1 = {}, nB2 = {}, nB3 = {};
    float  eA0 = 0, eA1 = 0, eA2 = 0, eA3 = 0;
    float  eB0 = 0, eB1 = 0, eB2 = 0, eB3 = 0;

    // B's streams sit at constant offsets from A's (adjacent samples):
    // noise: +NN*2 = 256 floats (1024B imm); exp: +NN = 128 floats (512B imm)
    const float* nzbA = noise + (size_t)sampA * (NN * 2) + n * 2;
    const float* edbA = exp_draws + (size_t)sampA * NN + n;

    if (wid < 2) {
        mu1 = mu[0]; negmu2 = -mu[1];
        g00 = sigma[0]; g01 = sigma[1]; g10 = sigma[2]; g11 = sigma[3];
        icn = ic[n];
        vA = v0[sampA * NN + n];        vB = v0[(sampA + 1) * NN + n];
        iA = i0[sampA * NN + n];        iB = i0[(sampA + 1) * NN + n];
        sA = s0[sampA * NN + n];        sB = s0[(sampA + 1) * NN + n];
        spA = softplus_np(vA);          spB = softplus_np(vB);
        nA0 = *(const float2*)(nzbA + 0ull * (NS * NN * 2));
        nB0 = *(const float2*)(nzbA + 0ull * (NS * NN * 2) + NN * 2);
        eA0 = edbA[0ull * (NS * NN)];   eB0 = edbA[0ull * (NS * NN) + NN];
        nA1 = *(const float2*)(nzbA + 1ull * (NS * NN * 2));
        nB1 = *(const float2*)(nzbA + 1ull * (NS * NN * 2) + NN * 2);
        eA1 = edbA[1ull * (NS * NN)];   eB1 = edbA[1ull * (NS * NN) + NN];
        nA2 = *(const float2*)(nzbA + 2ull * (NS * NN * 2));
        nB2 = *(const float2*)(nzbA + 2ull * (NS * NN * 2) + NN * 2);
        eA2 = edbA[2ull * (NS * NN)];   eB2 = edbA[2ull * (NS * NN) + NN];
        nA3 = *(const float2*)(nzbA + 3ull * (NS * NN * 2));
        nB3 = *(const float2*)(nzbA + 3ull * (NS * NN * 2) + NN * 2);
        eA3 = edbA[3ull * (NS * NN)];   eB3 = edbA[3ull * (NS * NN) + NN];
    }
    sync_lds();                           // w + zero rows visible

    if (wid < 2) {
        // ---------------- compute waves (both samples per lane) ----------------
        auto STEP = [&](int k, int blk, float2& nbA, float& ebA,
                        float2& nbB, float& ebB) {
            #pragma clang fp contract(off)
            const int t = blk * CH + k;
            const int par = k & 1;
            // --- pre-barrier: both s-chains + mask publish
            sA = sA + DTf * spA;
            sB = sB + DTf * spB;
            const bool kkA = (sA >= 0.0f), kkB = (sB >= 0.0f);
            const unsigned long long bmA = __ballot(kkA);
            const unsigned long long bmB = __ballot(kkB);
            if (l == 0) {
                mslot[par * 4 + wid] = bmA;       // [par][A][wid]
                mslot[par * 4 + 2 + wid] = bmB;   // [par][B][wid]
            }
            sync_lds();
            // --- consume prefetch, reissue t+PD (clamped)
            const float2 nzA = nbA, nzB = nbB;
            const float  edA = ebA, edB = ebB;
            const int tp = (t + PD) < NT ? (t + PD) : NT - 1;
            const float* pn = nzbA + (size_t)tp * (NS * NN * 2);
            const float* pe = edbA + (size_t)tp * (NS * NN);
            nbA = *(const float2*)(pn);
            nbB = *(const float2*)(pn + NN * 2);
            ebA = pe[0];
            ebB = pe[NN];
            // --- drift + noise, two independent chains (ILP bubble fill)
            const float dwA0 = nzA.x * SQDT, dwA1 = nzA.y * SQDT;
            const float dwB0 = nzB.x * SQDT, dwB1 = nzB.y * SQDT;
            const float nvA = (dwA0 * g00) + (dwA1 * g01);
            const float nvB = (dwB0 * g00) + (dwB1 * g01);
            const float niA = (dwA0 * g10) + (dwA1 * g11);
            const float niB = (dwB0 * g10) + (dwB1 * g11);
            const float ttA = (iA + icn) - vA;
            const float ttB = (iB + icn) - vB;
            const float vtA = (vA + DTf * (mu1 * ttA)) + nvA;
            const float vtB = (vB + DTf * (mu1 * ttB)) + nvB;
            const float itA = (iA + DTf * (negmu2 * iA)) + niA;
            const float itB = (iB + DTf * (negmu2 * iB)) + niB;
            const float spvA = softplus_np(vtA);
            const float spvB = softplus_np(vtB);
            // --- masks for both samples (broadcast LDS reads)
            unsigned long long m0A = mslot[par * 4 + 0];
            unsigned long long m1A = mslot[par * 4 + 1];
            unsigned long long m0B = mslot[par * 4 + 2];
            unsigned long long m1B = mslot[par * 4 + 3];
            // --- coupling, ascending order per sample (zero-row padding)
            auto extract = [&](unsigned long long& m0, unsigned long long& m1) -> int {
                const bool u0 = (m0 != 0);
                const unsigned long long m = u0 ? m0 : m1;
                const int b = m ? (int)__builtin_ctzll(m) : 99;
                const int r = (b == 99) ? 128 : ((u0 ? 0 : 64) + b);
                const unsigned long long m0n = m0 & (m0 - 1);
                const unsigned long long m1n = m1 & (m1 - 1);
                m0 = u0 ? m0n : m0;
                m1 = u0 ? m1 : m1n;
                return r;
            };
            float aA = 0.0f, aB = 0.0f;
            if (m0A | m1A) {
                const int r1 = extract(m0A, m1A);
                const int r2 = extract(m0A, m1A);
                const float q1 = wl[r1 * NN + n];
                const float q2 = wl[r2 * NN + n];
                aA = q1;  aA += q2;
                #pragma clang loop unroll(disable)
                while (m0A | m1A) {
                    const int r = extract(m0A, m1A);
                    aA += wl[r * NN + n];
                }
            }
            if (m0B | m1B) {
                const int r1 = extract(m0B, m1B);
                const int r2 = extract(m0B, m1B);
                const float q1 = wl[r1 * NN + n];
                const float q2 = wl[r2 * NN + n];
                aB = q1;  aB += q2;
                #pragma clang loop unroll(disable)
                while (m0B | m1B) {
                    const int r = extract(m0B, m1B);
                    aB += wl[r * NN + n];
                }
            }
            iA = itA + aA;                // unconditional add: bit-identical
            iB = itB + aB;
            vA = kkA ? 0.0f : vtA;        vB = kkB ? 0.0f : vtB;
            sA = kkA ? -edA : sA;         sB = kkB ? -edB : sB;
            spA = kkA ? LOGE2 : spvA;     spB = kkB ? LOGE2 : spvB;
            // --- stage outputs (both samples)
            float* rowA = obuf + (blk & 1) * OB_HALF + (k * 3) * NNP + n;
            rowA[0 * NNP] = vA;  rowA[1 * NNP] = iA;  rowA[2 * NNP] = sA;
            float* rowB = rowA + OBUF_PS;
            rowB[0 * NNP] = vB;  rowB[1 * NNP] = iB;  rowB[2 * NNP] = sB;
        };

        #pragma clang loop unroll(disable)
        for (int blk = 0; blk < NT / CH; ++blk) {
            STEP(0, blk, nA0, eA0, nB0, eB0);
            STEP(1, blk, nA1, eA1, nB1, eB1);
            STEP(2, blk, nA2, eA2, nB2, eB2);
            STEP(3, blk, nA3, eA3, nB3, eB3);
            STEP(4, blk, nA0, eA0, nB0, eB0);
            STEP(5, blk, nA1, eA1, nB1, eB1);
            STEP(6, blk, nA2, eA2, nB2, eB2);
            STEP(7, blk, nA3, eA3, nB3, eB3);
        }
    } else {
        // ---------------- flush wave (both samples) ----------------
        auto flush3 = [&](int ss, int h, int tb0, int kk) {
            const float* ob2 = obuf + ss * OBUF_PS + h * OB_HALF;
            float* ox = outbA + (size_t)ss * (NN * NT * 3);
            #pragma unroll
            for (int j = 3 * kk; j < 3 * kk + 3; ++j) {
                const int f = j * 64 + l;        // float2 slot 0..1535
                const int nn2 = f / 12;          // neuron
                const int da = 2 * (f - nn2 * 12);
                const float x = ob2[(da    ) * NNP + nn2];
                const float y = ob2[(da + 1) * NNP + nn2];
                *(float2*)(ox + (size_t)nn2 * (NT * 3) + (size_t)tb0 * 3 + da) =
                    make_float2(x, y);
            }
        };
        #pragma clang loop unroll(disable)
        for (int blk = 0; blk < NT / CH; ++blk) {
            #pragma clang loop unroll(disable)
            for (int k = 0; k < CH; ++k) {
                sync_lds();               // match compute waves' per-step barrier
                if (blk > 0) {
                    flush3(0, (blk - 1) & 1, (blk - 1) * CH, k);
                    flush3(1, (blk - 1) & 1, (blk - 1) * CH, k);
                }
            }
        }
    }

    // tail: last half-buffer's writes land after the loop's final barrier
    sync_lds();
    if (wid == 2) {
        #pragma unroll
        for (int ss = 0; ss < 2; ++ss) {
            const float* ob2 = obuf + ss * OBUF_PS + ((NT / CH - 1) & 1) * OB_HALF;
            float* ox = outbA + (size_t)ss * (NN * NT * 3);
            #pragma unroll
            for (int j = 0; j < 24; ++j) {
                const int f = j * 64 + l;
                const int nn2 = f / 12;
                const int da = 2 * (f - nn2 * 12);
                const float x = ob2[(da    ) * NNP + nn2];
                const float y = ob2[(da + 1) * NNP + nn2];
                *(float2*)(ox + (size_t)nn2 * (NT * 3) + (size_t)(NT - CH) * 3 + da) =
                    make_float2(x, y);
            }
        }
    }
}

extern "C" void kernel_launch(void* const* d_in, const int* in_sizes, int n_in,
                              void* d_out, int out_size, void* d_ws, size_t ws_size,
                              hipStream_t stream) {
    const float* w         = (const float*)d_in[0];
    const float* ic        = (const float*)d_in[1];
    const float* v0        = (const float*)d_in[2];
    const float* i0        = (const float*)d_in[3];
    const float* s0        = (const float*)d_in[4];
    const float* mu        = (const float*)d_in[5];
    const float* sigma     = (const float*)d_in[6];
    const float* noise     = (const float*)d_in[7];
    const float* exp_draws = (const float*)d_in[8];
    float* out = (float*)d_out;

    (void)hipFuncSetAttribute((const void*)snn_scan_kernel,
                              hipFuncAttributeMaxDynamicSharedMemorySize,
                              LDS_BYTES);

    // 2 samples per WAVE-PAIR: dual independent chains per lane fill
    // dependency bubbles; barrier structure unchanged (3 symmetric waves)
    snn_scan_kernel<<<dim3(NS / 2), dim3(192), LDS_BYTES, stream>>>(
        w, ic, v0, i0, s0, mu, sigma, noise, exp_draws, out);
}